// Round 7
// baseline (409.936 us; speedup 1.0000x reference)
//
#include <hip/hip_runtime.h>
#include <hip/hip_bf16.h>
#include <stdint.h>

#define NNODES 100000
#define NEDGES 640000
#define CIN 128
#define EDIM 64
#define C2 256
#define LN_EPS 1e-5f
#define NW 8192            // gather waves (2048 blocks x 4)
#define PP 79              // ceil(NEDGES / NW)

typedef __attribute__((ext_vector_type(8))) short bf16x8;
typedef __attribute__((ext_vector_type(4))) float f32x4;

__device__ __forceinline__ ushort f2bf(float f) {
    uint32_t u = __float_as_uint(f);
    uint32_t r = (u + 0x7fffu + ((u >> 16) & 1u)) >> 16;   // RNE
    return (ushort)r;
}
__device__ __forceinline__ uint32_t pack2(float a, float b) {
    return (uint32_t)f2bf(a) | ((uint32_t)f2bf(b) << 16);
}
__device__ __forceinline__ float bf2f_lo(uint32_t u) { return __uint_as_float(u << 16); }
__device__ __forceinline__ float bf2f_hi(uint32_t u) { return __uint_as_float(u & 0xffff0000u); }

union U16 { uint4 u; bf16x8 v; };

// ---------------------------------------------------------------------------
// k_prep: (a) x -> bf16-packed xbf (halves random gather bytes, L3-resident)
//         (b) W1,W2 -> transposed bf16 W1T[c][k], W2T[c][k] in global
//         (c) zero cursor (compute-queue: captured memset = blit, ~91us r3)
// ---------------------------------------------------------------------------
__global__ __launch_bounds__(256) void k_prep(
    const float* __restrict__ x, const float* __restrict__ W1,
    const float* __restrict__ W2, uint32_t* __restrict__ xbf,
    ushort* __restrict__ W1T, ushort* __restrict__ W2T,
    int* __restrict__ cursor)
{
    const int bid = blockIdx.x;
    if (bid < 6250) {                                   // xbf: 1.6M threads
        const int i = bid * 256 + threadIdx.x;
        const float4* xg = (const float4*)x;
        const float4 v0 = xg[i * 2];
        const float4 v1 = xg[i * 2 + 1];
        uint4 o;
        o.x = pack2(v0.x, v0.y); o.y = pack2(v0.z, v0.w);
        o.z = pack2(v1.x, v1.y); o.w = pack2(v1.z, v1.w);
        ((uint4*)xbf)[i] = o;
    } else if (bid < 6506) {                            // weight transpose
        const int idx = (bid - 6250) * 256 + threadIdx.x;   // [0, 65536)
        if (idx < 32768) {
            const int k = idx >> 8, c = idx & 255;
            W1T[c * 128 + k] = f2bf(W1[idx]);
        } else {
            const int j = idx - 32768;
            const int k = j >> 7, c = j & 127;
            W2T[c * 256 + k] = f2bf(W2[j]);
        }
    } else {                                            // cursor zero
        const int n = (bid - 6506) * 256 + threadIdx.x;
        if (n < NNODES) cursor[n] = 0;
    }
}

// ---------------------------------------------------------------------------
// CSR build: histogram -> 2-level exclusive scan -> fill (packed int2) + part.
// ---------------------------------------------------------------------------
__global__ __launch_bounds__(256) void k_hist(const int* __restrict__ ei,
                                              int* __restrict__ counts)
{
    const int e = blockIdx.x * 256 + threadIdx.x;
    atomicAdd(&counts[ei[e]], 1);
}

#define CHUNK 98   // 1024 * 98 >= 100000

__global__ __launch_bounds__(256) void k_scanA(const int* __restrict__ counts,
                                               int* __restrict__ chunks)
{
    const int c = blockIdx.x * 256 + threadIdx.x;
    const int n0 = c * CHUNK;
    const int n1 = min(n0 + CHUNK, NNODES);
    int s = 0;
    for (int n = n0; n < n1; ++n) s += counts[n];
    chunks[c] = s;
}

__global__ __launch_bounds__(1024) void k_scanB(int* __restrict__ chunks)
{
    __shared__ int ws[16];
    const int t = threadIdx.x, lane = t & 63, wv = t >> 6;
    const int v = chunks[t];
    int s = v;
#pragma unroll
    for (int off = 1; off < 64; off <<= 1) {
        const int u = __shfl_up(s, off);
        if (lane >= off) s += u;
    }
    if (lane == 63) ws[wv] = s;
    __syncthreads();
    if (t < 16) {
        const int u = ws[t];
        int ss = u;
#pragma unroll
        for (int off = 1; off < 16; off <<= 1) {
            const int uu = __shfl_up(ss, off);
            if (lane >= off) ss += uu;
        }
        ws[t] = ss - u;
    }
    __syncthreads();
    chunks[t] = s - v + ws[wv];
}

__global__ __launch_bounds__(256) void k_scanC(int* __restrict__ cursor,
                                               const int* __restrict__ chunks,
                                               int* __restrict__ rowptr)
{
    const int c = blockIdx.x * 256 + threadIdx.x;
    const int n0 = c * CHUNK;
    const int n1 = min(n0 + CHUNK, NNODES);
    int run = chunks[c];
    for (int n = n0; n < n1; ++n) {
        const int d = cursor[n];
        rowptr[n] = run;
        cursor[n] = run;
        run += d;
    }
    if (n1 == NNODES && n0 < NNODES) rowptr[NNODES] = run;
}

// fill (blocks 0..2499) + node-aligned partition (blocks 2500..)
__global__ __launch_bounds__(256) void k_fillp(const int* __restrict__ ei,
                                               int* __restrict__ cursor,
                                               int2* __restrict__ es,
                                               const int* __restrict__ rowptr,
                                               int* __restrict__ naw)
{
    const int bid = blockIdx.x;
    if (bid < 2500) {
        const int e = bid * 256 + threadIdx.x;
        const int d = ei[e];
        const int pos = atomicAdd(&cursor[d], 1);
        int2 v; v.x = e; v.y = ei[NEDGES + e];
        es[pos] = v;                                    // one 8B scatter
    } else {
        const int w = (bid - 2500) * 256 + threadIdx.x;
        if (w > NW) return;
        if (w == NW) { naw[w] = NNODES; return; }
        const int target = min(w * PP, NEDGES);
        int lo = 0, hi = NNODES;
        while (lo < hi) {
            const int mid = (lo + hi) >> 1;
            if (rowptr[mid] < target) lo = mid + 1; else hi = mid;
        }
        naw[w] = lo;
    }
}

// ---------------------------------------------------------------------------
// k_edge: fused edge-GEMM + gather, software-pipelined one 16-edge tile ahead.
// Wave owns nodes [naw[w], naw[w+1]) (node-aligned, ~79 edges). Per tile:
//   prev iter issued this tile's x-gather (16 x 4B bf16) + ea rows -> latency
//   hidden under MFMA+consume. Flush boundaries from scalar rowptr node-walk
//   (no dstS); degree-0 nodes flushed as zeros in the walk.
// ---------------------------------------------------------------------------
__global__ __launch_bounds__(256, 3) void k_edge(
    const uint32_t* __restrict__ xbf, const float* __restrict__ ea,
    const float* __restrict__ We, const float* __restrict__ be,
    const int2* __restrict__ es, const int* __restrict__ naw,
    const int* __restrict__ rowptr, uint32_t* __restrict__ hbf)
{
    __shared__ float msgl[4 * 16 * 128];          // 32 KB: 8 KB per wave
    const int tid = threadIdx.x;
    const int l = tid & 63, q = l >> 4, m16 = l & 15;
    const int wv = tid >> 6;
    const int w = blockIdx.x * 4 + wv;

    // B fragments: bfw[ks][t][j] = We[k=ks*32+q*8+j][c=m16+16t]
    bf16x8 bfw[2][8];
#pragma unroll
    for (int ks = 0; ks < 2; ++ks)
#pragma unroll
        for (int t = 0; t < 8; ++t) {
            const int c = m16 + 16 * t;
#pragma unroll
            for (int j = 0; j < 8; ++j)
                bfw[ks][t][j] = (short)f2bf(We[(ks * 32 + q * 8 + j) * CIN + c]);
        }
    const float2 bev = ((const float2*)be)[l];

    const int n0 = __builtin_amdgcn_readfirstlane(naw[w]);
    const int n1 = __builtin_amdgcn_readfirstlane(naw[w + 1]);
    if (n0 >= n1) return;
    const int ps = __builtin_amdgcn_readfirstlane(rowptr[n0]);
    const int pe = __builtin_amdgcn_readfirstlane(rowptr[n1]);
    if (ps >= pe) {                               // all-empty range
        for (int nn = n0; nn < n1; ++nn) hbf[(size_t)nn * 64 + l] = 0;
        return;
    }

    char* msb = (char*)msgl + wv * 8192;
    const int pmax = NEDGES - 1;

    int n = n0;
    int bnd = __builtin_amdgcn_readfirstlane(rowptr[n + 1]);
    float a0 = 0.f, a1 = 0.f;

    // ---- prologue: tile 0 idx + x + ea ----
    int2 idA = es[min(ps + m16, pmax)];
    uint xrA[16];
    float4 eaR[4];
#pragma unroll
    for (int jj = 0; jj < 16; ++jj) {
        const int sj = __builtin_amdgcn_readlane(idA.y, jj);
        xrA[jj] = xbf[(size_t)sj * 64 + l];
    }
    {
        const float* ar = ea + (size_t)idA.x * EDIM;
        eaR[0] = *(const float4*)(ar + q * 8);
        eaR[1] = *(const float4*)(ar + q * 8 + 4);
        eaR[2] = *(const float4*)(ar + 32 + q * 8);
        eaR[3] = *(const float4*)(ar + 32 + q * 8 + 4);
    }

    const int ntile = (pe - ps + 15) >> 4;

#define CSTEP(jj)                                                           \
    {                                                                       \
        while (p0 + (jj) == bnd) {                                          \
            hbf[(size_t)n * 64 + l] = pack2(a0, a1);                        \
            a0 = 0.f; a1 = 0.f; ++n;                                        \
            bnd = __builtin_amdgcn_readfirstlane(rowptr[n + 1]);            \
        }                                                                   \
        const uint32_t xu = xrA[jj];                                        \
        const float2 mv = *(const float2*)(msb + (jj) * 512 +               \
                                 ((8 * l) ^ (((jj) & 7) << 4)));            \
        a0 += fmaxf(bf2f_lo(xu) + mv.x + bev.x, 0.f);                       \
        a1 += fmaxf(bf2f_hi(xu) + mv.y + bev.y, 0.f);                       \
    }

    for (int t = 0; t < ntile; ++t) {
        const int p0 = ps + t * 16;
        const bool haveNext = (t + 1 < ntile);

        // A-convert (eaR loaded last iteration / prologue)
        bf16x8 A0, A1;
        A0[0] = (short)f2bf(eaR[0].x); A0[1] = (short)f2bf(eaR[0].y);
        A0[2] = (short)f2bf(eaR[0].z); A0[3] = (short)f2bf(eaR[0].w);
        A0[4] = (short)f2bf(eaR[1].x); A0[5] = (short)f2bf(eaR[1].y);
        A0[6] = (short)f2bf(eaR[1].z); A0[7] = (short)f2bf(eaR[1].w);
        A1[0] = (short)f2bf(eaR[2].x); A1[1] = (short)f2bf(eaR[2].y);
        A1[2] = (short)f2bf(eaR[2].z); A1[3] = (short)f2bf(eaR[2].w);
        A1[4] = (short)f2bf(eaR[3].x); A1[5] = (short)f2bf(eaR[3].y);
        A1[6] = (short)f2bf(eaR[3].z); A1[7] = (short)f2bf(eaR[3].w);

        // issue next tile's index load early
        int2 idB;
        if (haveNext) idB = es[min(p0 + 16 + m16, pmax)];

        // MFMA -> wave-private LDS (two 64-col halves, 16 VGPR acc)
#pragma unroll
        for (int hf = 0; hf < 2; ++hf) {
            f32x4 acc4[4];
#pragma unroll
            for (int t4 = 0; t4 < 4; ++t4) acc4[t4] = (f32x4){0.f, 0.f, 0.f, 0.f};
#pragma unroll
            for (int t4 = 0; t4 < 4; ++t4) {
                acc4[t4] = __builtin_amdgcn_mfma_f32_16x16x32_bf16(A0, bfw[0][hf * 4 + t4], acc4[t4], 0, 0, 0);
                acc4[t4] = __builtin_amdgcn_mfma_f32_16x16x32_bf16(A1, bfw[1][hf * 4 + t4], acc4[t4], 0, 0, 0);
            }
#pragma unroll
            for (int t4 = 0; t4 < 4; ++t4) {
                const int col = m16 + 16 * (hf * 4 + t4);
#pragma unroll
                for (int r = 0; r < 4; ++r) {
                    const int row = q * 4 + r;
                    *(float*)(msb + row * 512 + ((4 * col) ^ ((row & 7) << 4))) = acc4[t4][r];
                }
            }
        }

        // issue next tile's x-gather + ea row (hidden under consume below)
        uint xrB[16];
        if (haveNext) {
#pragma unroll
            for (int jj = 0; jj < 16; ++jj) {
                const int sj = __builtin_amdgcn_readlane(idB.y, jj);
                xrB[jj] = xbf[(size_t)sj * 64 + l];
            }
            const float* ar = ea + (size_t)idB.x * EDIM;
            eaR[0] = *(const float4*)(ar + q * 8);
            eaR[1] = *(const float4*)(ar + q * 8 + 4);
            eaR[2] = *(const float4*)(ar + 32 + q * 8);
            eaR[3] = *(const float4*)(ar + 32 + q * 8 + 4);
        }

        // consume this tile
        if (p0 + 16 <= pe) {
            CSTEP(0)  CSTEP(1)  CSTEP(2)  CSTEP(3)
            CSTEP(4)  CSTEP(5)  CSTEP(6)  CSTEP(7)
            CSTEP(8)  CSTEP(9)  CSTEP(10) CSTEP(11)
            CSTEP(12) CSTEP(13) CSTEP(14) CSTEP(15)
        } else {
            const int lim = pe - p0;
#pragma unroll
            for (int jj = 0; jj < 16; ++jj)
                if (jj < lim) CSTEP(jj)
        }

        // rotate pipeline registers
        if (haveNext) {
            idA = idB;
#pragma unroll
            for (int jj = 0; jj < 16; ++jj) xrA[jj] = xrB[jj];
        }
    }
    // final flush: current node + trailing (possibly empty) nodes
    while (n < n1) {
        hbf[(size_t)n * 64 + l] = pack2(a0, a1);
        a0 = 0.f; a1 = 0.f; ++n;
    }
#undef CSTEP
}

// ---------------------------------------------------------------------------
// Fused MLP: out = relu(LN(h@W1+b1))@W2 + b2, h = (1+eps)x + msum(hbf).
// LDS = 64 KB only (w1t; h1 tiles overlay it) -> 2 blocks/CU.
// W1T staged from pre-transposed bf16 global (4096 x 16B chunks); W2 B-frags
// read directly from L2-hot W2T global; bias/gamma/beta from global (L1).
// ---------------------------------------------------------------------------
__global__ __launch_bounds__(512, 4) void k23_fused(
    const uint32_t* __restrict__ hbf, const float* __restrict__ x,
    const float* __restrict__ eps, const ushort* __restrict__ W1T,
    const ushort* __restrict__ W2T, const float* __restrict__ b1,
    const float* __restrict__ gamma, const float* __restrict__ beta,
    const float* __restrict__ b2, float* __restrict__ out)
{
    __shared__ ushort w1t[CIN * C2];      // 64 KB (then: h1 tiles, 8KB/wave)

    const int tid = threadIdx.x;
    {   // stage W1T -> LDS, swizzled. 65536 B = 4096 chunks (8 iters/thread)
        const uint4* w1g = (const uint4*)W1T;
#pragma unroll
        for (int i = tid; i < 4096; i += 512) {
            const int c = i >> 4, inb = (i & 15) << 4;
            *(uint4*)((char*)w1t + c * 256 + (inb ^ ((c & 15) << 4))) = w1g[i];
        }
    }
    const float s1p = 1.0f + eps[0];
    __syncthreads();

    const int l = tid & 63, q = l >> 4, m16 = l & 15;
    const int w = tid >> 6;
    const int n0 = blockIdx.x * 128 + w * 16;
    const int rowA = min(n0 + m16, NNODES - 1);

    // ---- GEMM1: [16 x 128] @ [128 x 256], A = (1+eps)x + msum on the fly ----
    f32x4 acc[16];
#pragma unroll
    for (int t = 0; t < 16; ++t) acc[t] = (f32x4){0.f, 0.f, 0.f, 0.f};

    const char* w1b = (const char*)w1t;
#pragma unroll
    for (int ks = 0; ks < 4; ++ks) {
        const uint4 su = *(const uint4*)(hbf + (size_t)rowA * 64 + ks * 16 + q * 4);
        const float* xp = x + (size_t)rowA * CIN + ks * 32 + q * 8;
        const float4 xa = *(const float4*)xp;
        const float4 xb = *(const float4*)(xp + 4);
        U16 A;
        A.v[0] = (short)f2bf(fmaf(s1p, xa.x, bf2f_lo(su.x)));
        A.v[1] = (short)f2bf(fmaf(s1p, xa.y, bf2f_hi(su.x)));
        A.v[2] = (short)f2bf(fmaf(s1p, xa.z, bf2f_lo(su.y)));
        A.v[3] = (short)f2bf(fmaf(s1p, xa.w, bf2f_hi(su.y)));
        A.v[4] = (short)f2bf(fmaf(s1p, xb.x, bf2f_lo(su.z)));
        A.v[5] = (short)f2bf(fmaf(s1p, xb.y, bf2f_hi(su.z)));
        A.v[6] = (short)f2bf(fmaf(s1p, xb.z, bf2f_lo(su.w)));
        A.v[7] = (short)f2bf(fmaf(s1p, xb.w, bf2f_hi(su.w)));
        const int inrow = (ks * 64 + q * 16) ^ (m16 << 4);
#pragma unroll
        for (int t = 0; t < 16; ++t) {
            U16 B; B.u = *(const uint4*)(w1b + (size_t)(m16 + 16 * t) * 256 + inrow);
            acc[t] = __builtin_amdgcn_mfma_f32_16x16x32_bf16(A.v, B.v, acc[t], 0, 0, 0);
        }
    }

    // ---- bias + LayerNorm + ReLU (in-register, 16-lane reduce) ----
    float s[4] = {0.f, 0.f, 0.f, 0.f}, sq[4] = {0.f, 0.f, 0.f, 0.f};
#pragma unroll
    for (int t = 0; t < 16; ++t) {
        const float bb = b1[m16 + 16 * t];
#pragma unroll
        for (int r = 0; r < 4; ++r) {
            acc[t][r] += bb;
            s[r]  += acc[t][r];
            sq[r] += acc[t][r] * acc[t][r];
        }
    }
#pragma unroll
    for (int off = 1; off < 16; off <<= 1)
#pragma unroll
        for (int r = 0; r < 4; ++r) {
            s[r]  += __shfl_xor(s[r],  off);
            sq[r] += __shfl_xor(sq[r], off);
        }
    float mu[4], is[4];
#pragma unroll
    for (int r = 0; r < 4; ++r) {
        mu[r] = s[r] * (1.0f / 256.0f);
        const float var = sq[r] * (1.0f / 256.0f) - mu[r] * mu[r];
        is[r] = rsqrtf(var + LN_EPS);
    }

    __syncthreads();   // all waves done reading w1t -> safe to overwrite

    // ---- h1 tile (16 x 256 bf16) into own w1t slice ----
    char* hls = (char*)w1t + w * 8192;
#pragma unroll
    for (int t = 0; t < 16; ++t) {
        const int c = m16 + 16 * t;
        const float g = gamma[c], b = beta[c];
#pragma unroll
        for (int r = 0; r < 4; ++r) {
            const int row = q * 4 + r;
            const float o = fmaxf((acc[t][r] - mu[r]) * is[r] * g + b, 0.0f);
            *(ushort*)(hls + row * 512 + ((2 * c) ^ (row << 4))) = f2bf(o);
        }
    }
    __syncthreads();

    // ---- GEMM2: [16 x 256] @ [256 x 128], B from L2-hot W2T global ----
    f32x4 acc2[8];
#pragma unroll
    for (int t = 0; t < 8; ++t) acc2[t] = (f32x4){0.f, 0.f, 0.f, 0.f};

    const char* w2g = (const char*)W2T;
#pragma unroll
    for (int ks = 0; ks < 8; ++ks) {
        const int inrow = (ks * 64 + q * 16) ^ (m16 << 4);
        const int inrow2 = ks * 64 + q * 16;
        U16 A; A.u = *(const uint4*)(hls + m16 * 512 + inrow);
#pragma unroll
        for (int t = 0; t < 8; ++t) {
            U16 B; B.u = *(const uint4*)(w2g + (size_t)(m16 + 16 * t) * 512 + inrow2);
            acc2[t] = __builtin_amdgcn_mfma_f32_16x16x32_bf16(A.v, B.v, acc2[t], 0, 0, 0);
        }
    }
#pragma unroll
    for (int t = 0; t < 8; ++t) {
        const int c = m16 + 16 * t;
        const float bb = b2[c];
#pragma unroll
        for (int r = 0; r < 4; ++r) {
            const int row = n0 + q * 4 + r;
            if (row < NNODES)
                out[(size_t)row * CIN + c] = acc2[t][r] + bb;
        }
    }
}

// ---------------------------------------------------------------------------
extern "C" void kernel_launch(void* const* d_in, const int* in_sizes, int n_in,
                              void* d_out, int out_size, void* d_ws, size_t ws_size,
                              hipStream_t stream)
{
    const float* x     = (const float*)d_in[0];
    const int*   ei    = (const int*)d_in[1];
    const float* ea    = (const float*)d_in[2];
    const float* We    = (const float*)d_in[3];
    const float* be    = (const float*)d_in[4];
    const float* W1    = (const float*)d_in[5];
    const float* b1    = (const float*)d_in[6];
    const float* gamma = (const float*)d_in[7];
    const float* beta  = (const float*)d_in[8];
    const float* W2    = (const float*)d_in[9];
    const float* b2    = (const float*)d_in[10];
    const float* eps   = (const float*)d_in[11];

    // ws layout, ~57.3 MB of ~655 MB:
    char* wsB = (char*)d_ws;
    uint32_t* hbf   = (uint32_t*)wsB;                       // 25,600,000 B
    int*      rowptr= (int*)(wsB + 25600000);               //    400,004 B
    int*      cursor= (int*)(wsB + 26001408);               //    400,000 B
    int2*     es    = (int2*)(wsB + 26401408);              //  5,120,000 B
    int*      chunks= (int*)(wsB + 31522816);               //      4,096 B
    int*      naw   = (int*)(wsB + 31526912);               //     32,772 B
    uint32_t* xbf   = (uint32_t*)(wsB + 31561728);          // 25,600,000 B
    ushort*   W1T   = (ushort*)(wsB + 57161728);            //     65,536 B
    ushort*   W2T   = (ushort*)(wsB + 57227264);            //     65,536 B

    k_prep <<<6897, 256, 0, stream>>>(x, W1, W2, xbf, W1T, W2T, cursor);
    k_hist <<<NEDGES / 256, 256, 0, stream>>>(ei, cursor);
    k_scanA<<<4, 256, 0, stream>>>(cursor, chunks);
    k_scanB<<<1, 1024, 0, stream>>>(chunks);
    k_scanC<<<4, 256, 0, stream>>>(cursor, chunks, rowptr);
    k_fillp<<<2500 + 33, 256, 0, stream>>>(ei, cursor, es, rowptr, naw);

    k_edge <<<NW / 4, 256, 0, stream>>>(xbf, ea, We, be, es, naw, rowptr, hbf);

    k23_fused<<<(NNODES + 127) / 128, 512, 0, stream>>>(hbf, x, eps, W1T, W2T,
                                                        b1, gamma, beta, b2,
                                                        (float*)d_out);
}